// Round 1
// baseline (661.214 us; speedup 1.0000x reference)
//
#include <hip/hip_runtime.h>

// B=8, H=16, S=1024, D=64. Outputs: context (B,H,S,D) then attn (B,H,S,S), fp32.
#define Sn 1024
#define Dn 64
#define BHn 128

// ---------------------------------------------------------------------------
// K1: scores = Q@K^T, mask -> 1e-9, exp (no max-sub needed: |score|<~64),
// row-sum via 32-lane shuffle, write normalized attn once.
// Block: 256 threads; tile: 32 q-rows x full 1024 k.
// Thread tile: 4 q x 32 k (8 groups of 4 consecutive k, stride 128).
// ---------------------------------------------------------------------------
__global__ __launch_bounds__(256) void k_scores_softmax(
    const float* __restrict__ Q, const float* __restrict__ Kmat,
    const int* __restrict__ M, float* __restrict__ A)
{
    const int blk = blockIdx.x;
    const int bh  = blk >> 5;          // 32 q-tiles per (b,h)
    const int q0  = (blk & 31) << 5;   // q-tile base

    const float* Qb = Q    + (size_t)bh * Sn * Dn + (size_t)q0 * Dn;
    const float* Kb = Kmat + (size_t)bh * Sn * Dn;
    const int*   Mb = M    + (size_t)bh * Sn * Sn;
    float*       Ab = A    + (size_t)bh * Sn * Sn;

    const int t  = threadIdx.x;
    const int qg = t >> 5;   // 0..7  -> q rows qg*4..qg*4+3
    const int kg = t & 31;   // 0..31 -> k cols kg*4 + j*128

    __shared__ float Qs[8][36];    // [dd][q]  (padded)
    __shared__ float Ks[8][1028];  // [dd][k]  (padded)

    float s[4][32];
    #pragma unroll
    for (int i = 0; i < 4; ++i)
        #pragma unroll
        for (int j = 0; j < 32; ++j) s[i][j] = 0.f;

    for (int d0 = 0; d0 < Dn; d0 += 8) {
        __syncthreads();
        {   // stage Q: 32 q x 8 dd, one float per thread
            const int q = t >> 3, dd = t & 7;
            Qs[dd][q] = Qb[q * Dn + d0 + dd];
        }
        {   // stage K transposed: 1024 k x 8 dd; 4 rows per thread
            const int kb = t << 2;
            #pragma unroll
            for (int r = 0; r < 4; ++r) {
                const float4* src = (const float4*)(Kb + (size_t)(kb + r) * Dn + d0);
                const float4 a = src[0], b = src[1];
                Ks[0][kb + r] = a.x; Ks[1][kb + r] = a.y;
                Ks[2][kb + r] = a.z; Ks[3][kb + r] = a.w;
                Ks[4][kb + r] = b.x; Ks[5][kb + r] = b.y;
                Ks[6][kb + r] = b.z; Ks[7][kb + r] = b.w;
            }
        }
        __syncthreads();
        #pragma unroll
        for (int dd = 0; dd < 8; ++dd) {
            const float4 qv = *(const float4*)&Qs[dd][qg << 2];
            const float qa[4] = {qv.x, qv.y, qv.z, qv.w};
            #pragma unroll
            for (int j = 0; j < 8; ++j) {
                const float4 kv = *(const float4*)&Ks[dd][(kg << 2) + (j << 7)];
                const float ka[4] = {kv.x, kv.y, kv.z, kv.w};
                #pragma unroll
                for (int i = 0; i < 4; ++i)
                    #pragma unroll
                    for (int r = 0; r < 4; ++r)
                        s[i][(j << 2) + r] = fmaf(qa[i], ka[r], s[i][(j << 2) + r]);
            }
        }
    }

    // mask + exp + row-sum + normalize + store
    #pragma unroll
    for (int i = 0; i < 4; ++i) {
        const int q = q0 + (qg << 2) + i;
        const int* mrow = Mb + (size_t)q * Sn;
        float sum = 0.f;
        #pragma unroll
        for (int j = 0; j < 8; ++j) {
            const int4 m = *(const int4*)&mrow[(kg << 2) + (j << 7)];
            // masked: score := 1e-9 -> exp == 1.0f in fp32
            const float e0 = m.x ? 1.0f : __expf(s[i][(j << 2) + 0]);
            const float e1 = m.y ? 1.0f : __expf(s[i][(j << 2) + 1]);
            const float e2 = m.z ? 1.0f : __expf(s[i][(j << 2) + 2]);
            const float e3 = m.w ? 1.0f : __expf(s[i][(j << 2) + 3]);
            s[i][(j << 2) + 0] = e0; s[i][(j << 2) + 1] = e1;
            s[i][(j << 2) + 2] = e2; s[i][(j << 2) + 3] = e3;
            sum += (e0 + e1) + (e2 + e3);
        }
        // reduce across the 32 threads (same qg) holding this row
        #pragma unroll
        for (int off = 16; off >= 1; off >>= 1)
            sum += __shfl_xor(sum, off);
        const float inv = 1.0f / sum;
        float* arow = Ab + (size_t)q * Sn;
        #pragma unroll
        for (int j = 0; j < 8; ++j) {
            float4 st;
            st.x = s[i][(j << 2) + 0] * inv;
            st.y = s[i][(j << 2) + 1] * inv;
            st.z = s[i][(j << 2) + 2] * inv;
            st.w = s[i][(j << 2) + 3] * inv;
            *(float4*)&arow[(kg << 2) + (j << 7)] = st;
        }
    }
}

// ---------------------------------------------------------------------------
// K2: context = attn @ V. Block tile: 128 q x 64 d, k-chunks of 32.
// Thread tile: 8 q x 4 d. attn staged transposed [k][q], V staged [k][d].
// ---------------------------------------------------------------------------
__global__ __launch_bounds__(256) void k_pv(
    const float* __restrict__ A, const float* __restrict__ V, float* __restrict__ C)
{
    const int blk = blockIdx.x;
    const int bh  = blk >> 3;
    const int q0  = (blk & 7) << 7;

    const float* Ab = A + (size_t)bh * Sn * Sn + (size_t)q0 * Sn;
    const float* Vb = V + (size_t)bh * Sn * Dn;
    float*       Cb = C + (size_t)bh * Sn * Dn + (size_t)q0 * Dn;

    const int t  = threadIdx.x;
    const int dg = t & 15;   // d = dg*4..dg*4+3
    const int qg = t >> 4;   // q = qg*8..qg*8+7

    __shared__ float As[32][132];  // [k][q] padded
    __shared__ float Vs[32][64];   // [k][d]

    float acc[8][4];
    #pragma unroll
    for (int i = 0; i < 8; ++i)
        #pragma unroll
        for (int r = 0; r < 4; ++r) acc[i][r] = 0.f;

    for (int kc = 0; kc < Sn; kc += 32) {
        __syncthreads();
        {   // stage attn tile 128q x 32k, transposed
            const int q = t >> 1, kh = (t & 1) << 4;
            const float* src = Ab + (size_t)q * Sn + kc + kh;
            #pragma unroll
            for (int c = 0; c < 4; ++c) {
                const float4 a = *(const float4*)(src + (c << 2));
                As[kh + (c << 2) + 0][q] = a.x;
                As[kh + (c << 2) + 1][q] = a.y;
                As[kh + (c << 2) + 2][q] = a.z;
                As[kh + (c << 2) + 3][q] = a.w;
            }
        }
        {   // stage V tile 32k x 64d
            const int kl = t >> 3, dd = (t & 7) << 3;
            const float4* src = (const float4*)(Vb + (size_t)(kc + kl) * Dn + dd);
            *(float4*)&Vs[kl][dd]     = src[0];
            *(float4*)&Vs[kl][dd + 4] = src[1];
        }
        __syncthreads();
        #pragma unroll
        for (int kl = 0; kl < 32; ++kl) {
            const float4 a0 = *(const float4*)&As[kl][qg << 3];
            const float4 a1 = *(const float4*)&As[kl][(qg << 3) + 4];
            const float4 v  = *(const float4*)&Vs[kl][dg << 2];
            const float aa[8] = {a0.x, a0.y, a0.z, a0.w, a1.x, a1.y, a1.z, a1.w};
            const float vv[4] = {v.x, v.y, v.z, v.w};
            #pragma unroll
            for (int i = 0; i < 8; ++i)
                #pragma unroll
                for (int r = 0; r < 4; ++r)
                    acc[i][r] = fmaf(aa[i], vv[r], acc[i][r]);
        }
    }

    #pragma unroll
    for (int i = 0; i < 8; ++i) {
        float4 st;
        st.x = acc[i][0]; st.y = acc[i][1]; st.z = acc[i][2]; st.w = acc[i][3];
        *(float4*)&Cb[(size_t)((qg << 3) + i) * Dn + (dg << 2)] = st;
    }
}

extern "C" void kernel_launch(void* const* d_in, const int* in_sizes, int n_in,
                              void* d_out, int out_size, void* d_ws, size_t ws_size,
                              hipStream_t stream) {
    const float* Q    = (const float*)d_in[0];
    const float* K    = (const float*)d_in[1];
    const float* V    = (const float*)d_in[2];
    const int*   mask = (const int*)d_in[3];

    float* ctx  = (float*)d_out;                                   // (B,H,S,D)
    float* attn = (float*)d_out + (size_t)BHn * Sn * Dn;           // (B,H,S,S)

    k_scores_softmax<<<BHn * 32, 256, 0, stream>>>(Q, K, mask, attn);
    k_pv<<<BHn * 8, 256, 0, stream>>>(attn, V, ctx);
}